// Round 7
// baseline (376.364 us; speedup 1.0000x reference)
//
#include <hip/hip_runtime.h>
#include <hip/hip_bf16.h>
#include <stdint.h>

#define B_ 2
#define T_ 2048
#define C_ 1024
#define H_ 16
#define D_ 64
#define F_ 4096
#define M_ (B_*T_)

typedef unsigned short ushort_t;
typedef __attribute__((ext_vector_type(8))) short short8;
typedef __attribute__((ext_vector_type(4))) float f32x4;

__device__ __forceinline__ float bf2f(ushort_t u) {
    union { unsigned u; float f; } c; c.u = ((unsigned)u) << 16; return c.f;
}
__device__ __forceinline__ ushort_t f2bf(float f) {
    union { float f; unsigned u; } c; c.f = f;
    unsigned u = c.u;
    unsigned r = (u + 0x7FFFu + ((u >> 16) & 1u)) >> 16;
    return (ushort_t)r;
}

__device__ __forceinline__ float fexp2(float x) { return __builtin_amdgcn_exp2f(x); }

// async global->LDS, 16B per lane. LDS dest = wave-uniform base + lane*16.
__device__ __forceinline__ void async16(void* lds, const void* g) {
    __builtin_amdgcn_global_load_lds(
        (const __attribute__((address_space(1))) unsigned int*)(uintptr_t)g,
        (__attribute__((address_space(3))) unsigned int*)(uintptr_t)lds,
        16, 0, 0);
}

// ---------------------------------------------------------------------------
// Batched transpose+cast of all 6 weights: out_bf16[c][r] = in_f32[r][c]
// ---------------------------------------------------------------------------
__global__ __launch_bounds__(256) void transpose_all_k(
    const float* __restrict__ Wq, const float* __restrict__ Wk,
    const float* __restrict__ Wv, const float* __restrict__ Wo,
    const float* __restrict__ W1, const float* __restrict__ W2,
    ushort_t* __restrict__ oq, ushort_t* __restrict__ ok,
    ushort_t* __restrict__ ov, ushort_t* __restrict__ oo,
    ushort_t* __restrict__ o1, ushort_t* __restrict__ o2) {
    __shared__ ushort_t tile[32][33];
    int id = blockIdx.x;
    const float* in; ushort_t* out; int R, Cc, bx, by;
    if (id < 4096) {
        int w = id >> 10, loc = id & 1023;
        in  = w == 0 ? Wq : w == 1 ? Wk : w == 2 ? Wv : Wo;
        out = w == 0 ? oq : w == 1 ? ok : w == 2 ? ov : oo;
        R = 1024; Cc = 1024; bx = loc & 31; by = loc >> 5;
    } else if (id < 8192) {
        int loc = id - 4096; in = W1; out = o1; R = 1024; Cc = 4096;
        bx = loc & 127; by = loc >> 7;
    } else {
        int loc = id - 8192; in = W2; out = o2; R = 4096; Cc = 1024;
        bx = loc & 31; by = loc >> 5;
    }
    int tx = threadIdx.x, ty = threadIdx.y;
    int x = bx * 32 + tx;
    int y0 = by * 32;
#pragma unroll
    for (int i = 0; i < 32; i += 8)
        tile[ty + i][tx] = f2bf(in[(size_t)(y0 + ty + i) * Cc + x]);
    __syncthreads();
    int x2 = y0 + tx;
    int y2 = bx * 32;
#pragma unroll
    for (int i = 0; i < 32; i += 8)
        out[(size_t)(y2 + ty + i) * R + x2] = tile[tx][ty + i];
}

// ---------------------------------------------------------------------------
// LayerNorm: fp32 input row of 1024, fp32 scale/shift, bf16 output.
// ---------------------------------------------------------------------------
__global__ __launch_bounds__(256) void ln_kernel(const float* __restrict__ xin,
                                                 const float* __restrict__ scale_p,
                                                 const float* __restrict__ shift_p,
                                                 ushort_t* __restrict__ out) {
    int row = blockIdx.x, t = threadIdx.x;
    int wv = t >> 6, lane = t & 63;
    const float* xr = xin + (size_t)row * 1024 + t * 4;
    float4 v = *(const float4*)xr;
    float f[4] = {v.x, v.y, v.z, v.w};
    float s = f[0] + f[1] + f[2] + f[3];
    float q = f[0]*f[0] + f[1]*f[1] + f[2]*f[2] + f[3]*f[3];
#pragma unroll
    for (int off = 1; off < 64; off <<= 1) {
        s += __shfl_xor(s, off, 64);
        q += __shfl_xor(q, off, 64);
    }
    __shared__ float sh_s[4], sh_q[4];
    if (lane == 0) { sh_s[wv] = s; sh_q[wv] = q; }
    __syncthreads();
    float S = sh_s[0] + sh_s[1] + sh_s[2] + sh_s[3];
    float Q = sh_q[0] + sh_q[1] + sh_q[2] + sh_q[3];
    float mean = S * (1.0f / 1024.0f);
    float var = Q * (1.0f / 1024.0f) - mean * mean;
    float rstd = rsqrtf(var + 1e-5f);
    float4 scv = *(const float4*)(scale_p + t * 4);
    float4 shv = *(const float4*)(shift_p + t * 4);
    ushort4 o;
    o.x = f2bf((f[0] - mean) * rstd * scv.x + shv.x);
    o.y = f2bf((f[1] - mean) * rstd * scv.y + shv.y);
    o.z = f2bf((f[2] - mean) * rstd * scv.z + shv.z);
    o.w = f2bf((f[3] - mean) * rstd * scv.w + shv.w);
    *(ushort4*)(out + (size_t)row * 1024 + t * 4) = o;
}

// ---------------------------------------------------------------------------
// GEMM, double-buffered m97 structure + conflict-free chunk swizzle +
// LDS-bounce coalesced bf16 epilogue.
//   prologue: STAGE(buf0, k=0); __syncthreads;
//   iter k:   STAGE(buf^1, k+1); ds_read+MFMA on buf; __syncthreads; swap.
// Staging/read swizzle: source chunk kc -> kc ^ ((row>>1)&3); read chunk
// hi -> hi ^ ((lo>>1)&3)  (2 lanes/bank = free, verified 0 conflicts R6).
// Epilogue (bf16 row-major outputs): acc -> LDS tile [32MT][128] with chunk
// swizzle col8 -> col8 ^ (hi<<1) (all 32 banks, 2 lanes/bank), barrier, then
// short8 reads + 256B-contiguous row stores (full 64B lines, no L2 RMW —
// the old 2B scalar stores caused 2.1x write amplification, R6 counters).
// XCD-chunked block swizzle (requires nwg % 8 == 0).
// C[M,N] = A[M,K](bf16) @ Bt[N,K](bf16)^T + bias; tile (32*MT) x 128, BK=32.
// EPI: 1 = +f32 residual, f32 out (already full-line, unchanged)
//      2 = gelu, bf16 out
//      3 = QKV split: seg0/1 -> q,k row-major bf16 [.][1024]; seg2 -> v^T
//          (seg is block-uniform: 128-col blocks never straddle segments)
// ---------------------------------------------------------------------------
template <int MT, int EPI>
__global__ __launch_bounds__(256) void gemm_bt(const ushort_t* __restrict__ A,
                                               const ushort_t* __restrict__ Bt,
                                               const float* __restrict__ b0,
                                               const float* __restrict__ b1,
                                               const float* __restrict__ b2,
                                               const float* __restrict__ res,
                                               void* __restrict__ out0,
                                               void* __restrict__ out1,
                                               void* __restrict__ out2,
                                               int M, int N, int K) {
    // union: staging (As 2x1024*MT | Bs 2x4096) / epilogue bounce (4096*MT)
    __shared__ ushort_t smem[2048 * MT + 8192];
    ushort_t* As = smem;
    ushort_t* Bs = smem + 2048 * MT;
    const int t = threadIdx.x;
    const int wv = t >> 6, lane = t & 63, lo = lane & 15, hi = lane >> 4;
    const int wr = wv >> 1, wc = wv & 1;
    const int swz8 = (hi ^ ((lo >> 1) & 3)) * 8;   // read-side chunk swizzle

    // XCD-chunked swizzle (dispatch id d -> XCD d%8; give each XCD a
    // contiguous chunk of the x-major tile order = complete row-panels)
    const int nwg = gridDim.x * gridDim.y;
    const int id = blockIdx.y * gridDim.x + blockIdx.x;
    const int swz = (id & 7) * (nwg >> 3) + (id >> 3);
    const int nb = swz % gridDim.x, mb = swz / gridDim.x;

    f32x4 acc[MT][4];
#pragma unroll
    for (int i = 0; i < MT; ++i)
#pragma unroll
        for (int j = 0; j < 4; ++j) acc[i][j] = (f32x4){0.f, 0.f, 0.f, 0.f};

    auto STAGE = [&](int bf, int k0) {
#pragma unroll
        for (int i = 0; i < MT / 2; ++i) {
            int c = i * 256 + t;
            int row = c >> 2, kc = c & 3;
            int kof = (kc ^ ((row >> 1) & 3)) * 8;   // pre-swizzled source chunk
            async16((char*)(As + bf * 1024 * MT) + (size_t)(i * 256 + wv * 64) * 16,
                    A + (size_t)(mb * 32 * MT + row) * K + k0 + kof);
        }
#pragma unroll
        for (int i = 0; i < 2; ++i) {
            int c = i * 256 + t;
            int row = c >> 2, kc = c & 3;
            int kof = (kc ^ ((row >> 1) & 3)) * 8;
            async16((char*)(Bs + bf * 4096) + (size_t)(i * 256 + wv * 64) * 16,
                    Bt + (size_t)(nb * 128 + row) * K + k0 + kof);
        }
    };

    STAGE(0, 0);
    __syncthreads();

    const int NI = K >> 5;
    int bf = 0;
    for (int ki = 0; ki < NI; ++ki) {
        if (ki + 1 < NI) STAGE(bf ^ 1, (ki + 1) << 5);

        short8 af[MT], bfr[4];
#pragma unroll
        for (int mi = 0; mi < MT; ++mi)
            af[mi] = *(const short8*)(As + bf * 1024 * MT + (wr * 16 * MT + mi * 16 + lo) * 32 + swz8);
#pragma unroll
        for (int ni = 0; ni < 4; ++ni)
            bfr[ni] = *(const short8*)(Bs + bf * 4096 + (wc * 64 + ni * 16 + lo) * 32 + swz8);
#pragma unroll
        for (int mi = 0; mi < MT; ++mi)
#pragma unroll
            for (int ni = 0; ni < 4; ++ni)
                acc[mi][ni] = __builtin_amdgcn_mfma_f32_16x16x32_bf16(
                    af[mi], bfr[ni], acc[mi][ni], 0, 0, 0);

        __syncthreads();   // drains vmcnt(0)+lgkm(0) AFTER compute; one barrier/iter
        bf ^= 1;
    }

    // ------------------------- epilogue -------------------------
    if (EPI == 1) {
        // f32 + residual: quarter-wave = 64B full lines, already coalesced
#pragma unroll
        for (int ni = 0; ni < 4; ++ni) {
            int n = nb * 128 + wc * 64 + ni * 16 + lo;
            float bn = b0[n];
#pragma unroll
            for (int mi = 0; mi < MT; ++mi)
#pragma unroll
                for (int r = 0; r < 4; ++r) {
                    int m = mb * 32 * MT + wr * 16 * MT + mi * 16 + 4 * hi + r;
                    size_t idx = (size_t)m * N + n;
                    ((float*)out0)[idx] = acc[mi][ni][r] + bn + res[idx];
                }
        }
        return;
    }

    if (EPI == 3 && nb >= 16) {
        // seg 2: v^T transposed ushort4 store (unchanged)
#pragma unroll
        for (int ni = 0; ni < 4; ++ni) {
            int n = nb * 128 + wc * 64 + ni * 16 + lo;
            int coln = n & 1023;
            float bn = b2[coln];
#pragma unroll
            for (int mi = 0; mi < MT; ++mi) {
                int m0 = mb * 32 * MT + wr * 16 * MT + mi * 16 + 4 * hi;
                ushort4 pk;
                pk.x = f2bf(acc[mi][ni][0] + bn);
                pk.y = f2bf(acc[mi][ni][1] + bn);
                pk.z = f2bf(acc[mi][ni][2] + bn);
                pk.w = f2bf(acc[mi][ni][3] + bn);
                *(ushort4*)((ushort_t*)out2 + (size_t)coln * M + m0) = pk;
            }
        }
        return;
    }

    // bf16 row-major (EPI==2, or EPI==3 seg 0/1): LDS-bounce coalesced store
    {
        ushort_t* obf;
        const float* bias;
        int rowlen;
        if (EPI == 3) {
            int seg = nb >> 3;
            obf = (ushort_t*)(seg ? out1 : out0);
            bias = seg ? b1 : b0;
            rowlen = 1024;
        } else {
            obf = (ushort_t*)out0;
            bias = b0;
            rowlen = N;
        }
        // write acc -> LDS tile [32*MT][128], chunk-swizzled (conflict-free)
#pragma unroll
        for (int ni = 0; ni < 4; ++ni) {
            int n = nb * 128 + wc * 64 + ni * 16 + lo;
            float bn = bias[EPI == 3 ? (n & 1023) : n];
#pragma unroll
            for (int mi = 0; mi < MT; ++mi)
#pragma unroll
                for (int r = 0; r < 4; ++r) {
                    float v = acc[mi][ni][r] + bn;
                    if (EPI == 2)
                        v = 0.5f * v * (1.0f + erff(v * 0.70710678118654752f));
                    int row = wr * 16 * MT + mi * 16 + 4 * hi + r;
                    int c8 = (wc * 8 + ni * 2 + (lo >> 3)) ^ (hi << 1);
                    smem[row * 128 + c8 * 8 + (lo & 7)] = f2bf(v);
                }
        }
        __syncthreads();
        // read short8 + store 256B-contiguous rows (full lines)
        const int TR = 2 * MT;   // (32*MT*16)/256
#pragma unroll
        for (int j = 0; j < TR; ++j) {
            int idx = j * 256 + t;
            int row = idx >> 4, c = idx & 15;
            int c_src = c ^ (((row >> 2) & 3) << 1);
            short8 val = *(const short8*)(smem + row * 128 + c_src * 8);
            int m = mb * 32 * MT + row;
            int ncol = nb * 128 + c * 8;
            if (EPI == 3) ncol &= 1023;
            *(short8*)(obf + (size_t)m * rowlen + ncol) = val;
        }
    }
}

// ---------------------------------------------------------------------------
// Causal flash attention: 64-row q-tiles, grid 1024 (32 qt x 32 bh),
// longest strips dispatched first; 4 blocks/CU (LDS = 40960).
// ---------------------------------------------------------------------------
__global__ __launch_bounds__(256) void attn_kernel(const ushort_t* __restrict__ q,
                                                   const ushort_t* __restrict__ k,
                                                   const ushort_t* __restrict__ vt,
                                                   ushort_t* __restrict__ ctx) {
    __shared__ ushort_t Ks[2][64 * 64];   // [buf][key][d], col-chunk swizzled
    __shared__ ushort_t VTs[2][64 * 64];  // [buf][d][key], col-chunk swizzled
    __shared__ ushort_t Ps[4][16 * 64];   // [wave][qrow][key], XOR-swizzled chunks

    const int t = threadIdx.x;
    const int wv = t >> 6, lane = t & 63, lo = lane & 15, hi = lane >> 4;
    const int id = blockIdx.x;             // 1024
    const int qt = 31 - (id >> 5);         // longest-first
    const int bh = id & 31, b = bh >> 4, h = bh & 15;
    const int q0 = qt * 64;
    const size_t headoff = (size_t)h * 64;
    const size_t rowbase = (size_t)b * T_ * 1024;
    const ushort_t* vbase = vt + headoff * (size_t)M_ + (size_t)b * T_;

    short8 qf[2];
    {
        const ushort_t* qp = q + rowbase + (size_t)(q0 + wv * 16 + lo) * 1024 + headoff;
        qf[0] = *(const short8*)(qp + hi * 8);
        qf[1] = *(const short8*)(qp + 32 + hi * 8);
    }

    float m_r = -1e30f, l_r = 0.f;
    f32x4 o_acc[4];
#pragma unroll
    for (int dt = 0; dt < 4; ++dt) o_acc[dt] = (f32x4){0.f, 0.f, 0.f, 0.f};

    const float SC = 0.18033688011112042f;  // 0.125 * log2(e)
    const f32x4 NEG4 = (f32x4){-1e30f, -1e30f, -1e30f, -1e30f};

    auto stage = [&](int bb, int kt) {
        const int k0s = kt * 64;
#pragma unroll
        for (int i = 0; i < 2; ++i) {
            int c = i * 256 + t;
            int row = c >> 3, c8 = c & 7;
            int gsw = c8 ^ (row & 7);
            async16((char*)&Ks[bb][0] + (size_t)(i * 256 + wv * 64) * 16,
                    k + rowbase + (size_t)(k0s + row) * 1024 + headoff + gsw * 8);
            async16((char*)&VTs[bb][0] + (size_t)(i * 256 + wv * 64) * 16,
                    vbase + (size_t)row * M_ + k0s + gsw * 8);
        }
    };

    ushort_t* Pw = Ps[wv];
    const int psw = lo & 7;

    stage(0, 0);
    for (int kt = 0; kt <= qt; ++kt) {
        const int bb = kt & 1;
        const int k0 = kt * 64;
        __syncthreads();
        if (kt < qt) stage(bb ^ 1, kt + 1);

        const int diff = q0 + wv * 16 - k0;   // >= 0 always (kt <= qt)
        const int cmax = diff >= 48 ? 3 : (diff >> 4);

        f32x4 sacc[4];
#pragma unroll
        for (int kt16 = 0; kt16 < 4; ++kt16) {
            if (kt16 <= cmax) {
                int row = kt16 * 16 + lo, sw = row & 7;
                short8 kf0 = *(const short8*)(&Ks[bb][0] + row * 64 + (hi ^ sw) * 8);
                short8 kf1 = *(const short8*)(&Ks[bb][0] + row * 64 + ((4 + hi) ^ sw) * 8);
                f32x4 z = (f32x4){0.f, 0.f, 0.f, 0.f};
                z = __builtin_amdgcn_mfma_f32_16x16x32_bf16(kf0, qf[0], z, 0, 0, 0);
                z = __builtin_amdgcn_mfma_f32_16x16x32_bf16(kf1, qf[1], z, 0, 0, 0);
#pragma unroll
                for (int r = 0; r < 4; ++r) sacc[kt16][r] = z[r] * SC;
            } else {
                sacc[kt16] = NEG4;
            }
        }
        if (diff < 64) {  // diagonal subtile: element mask key > qrow
            const int qrow = diff + lo;
#pragma unroll
            for (int r = 0; r < 4; ++r) {
                int key = cmax * 16 + 4 * hi + r;
                if (key > qrow) sacc[cmax][r] = -1e30f;
            }
        }

        // ---- online softmax (rows = lo), packed P spill ----
        float mx = -1e30f;
#pragma unroll
        for (int kt16 = 0; kt16 < 4; ++kt16)
#pragma unroll
            for (int r = 0; r < 4; ++r) mx = fmaxf(mx, sacc[kt16][r]);
        mx = fmaxf(mx, __shfl_xor(mx, 16, 64));
        mx = fmaxf(mx, __shfl_xor(mx, 32, 64));
        float mnew = fmaxf(m_r, mx);
        float alpha = fexp2(m_r - mnew);
        m_r = mnew;
        float rs = 0.f;
#pragma unroll
        for (int kt16 = 0; kt16 < 4; ++kt16) {
            float p0 = fexp2(sacc[kt16][0] - mnew);
            float p1 = fexp2(sacc[kt16][1] - mnew);
            float p2 = fexp2(sacc[kt16][2] - mnew);
            float p3 = fexp2(sacc[kt16][3] - mnew);
            rs += p0 + p1 + p2 + p3;
            ushort4 pk;
            pk.x = f2bf(p0); pk.y = f2bf(p1); pk.z = f2bf(p2); pk.w = f2bf(p3);
            // key s = kt16*16 + 4*hi + r -> chunk 2*kt16 + (hi>>1), offset 4*(hi&1)
            *(ushort4*)(Pw + lo * 64 + (((2 * kt16 + (hi >> 1)) ^ psw) << 3) + 4 * (hi & 1)) = pk;
        }
        rs += __shfl_xor(rs, 16, 64);
        rs += __shfl_xor(rs, 32, 64);
        l_r = l_r * alpha + rs;
#pragma unroll
        for (int r = 0; r < 4; ++r) {
            float ab = __shfl(alpha, 4 * hi + r, 64);
#pragma unroll
            for (int dt = 0; dt < 4; ++dt) o_acc[dt][r] *= ab;
        }

        // ---- read P fragments back (same-wave LDS, in-order) ----
        short8 pf0 = *(const short8*)(Pw + lo * 64 + ((hi ^ psw) << 3));
        short8 pf1 = *(const short8*)(Pw + lo * 64 + (((4 + hi) ^ psw) << 3));

        // ---- PV ----
#pragma unroll
        for (int dt = 0; dt < 4; ++dt) {
            int row = dt * 16 + lo, sw = row & 7;
            short8 vf0 = *(const short8*)(&VTs[bb][0] + row * 64 + (hi ^ sw) * 8);
            short8 vf1 = *(const short8*)(&VTs[bb][0] + row * 64 + ((4 + hi) ^ sw) * 8);
            o_acc[dt] = __builtin_amdgcn_mfma_f32_16x16x32_bf16(pf0, vf0, o_acc[dt], 0, 0, 0);
            o_acc[dt] = __builtin_amdgcn_mfma_f32_16x16x32_bf16(pf1, vf1, o_acc[dt], 0, 0, 0);
        }
    }

#pragma unroll
    for (int r = 0; r < 4; ++r) {
        float lb = __shfl(l_r, 4 * hi + r, 64);
        float inv = 1.0f / lb;
        size_t row = rowbase + (size_t)(q0 + wv * 16 + 4 * hi + r) * 1024 + headoff;
#pragma unroll
        for (int dt = 0; dt < 4; ++dt)
            ctx[row + dt * 16 + lo] = f2bf(o_acc[dt][r] * inv);
    }
}

// ---------------------------------------------------------------------------
extern "C" void kernel_launch(void* const* d_in, const int* in_sizes, int n_in,
                              void* d_out, int out_size, void* d_ws, size_t ws_size,
                              hipStream_t stream) {
    (void)in_sizes; (void)n_in; (void)out_size; (void)ws_size;
    const float* x    = (const float*)d_in[0];
    const float* Wq   = (const float*)d_in[1];
    const float* bq   = (const float*)d_in[2];
    const float* Wk   = (const float*)d_in[3];
    const float* bk   = (const float*)d_in[4];
    const float* Wv   = (const float*)d_in[5];
    const float* bv   = (const float*)d_in[6];
    const float* Wo   = (const float*)d_in[7];
    const float* bo   = (const float*)d_in[8];
    const float* W1   = (const float*)d_in[9];
    const float* b1   = (const float*)d_in[10];
    const float* W2   = (const float*)d_in[11];
    const float* b2   = (const float*)d_in[12];
    const float* ln1s = (const float*)d_in[13];
    const float* ln1b = (const float*)d_in[14];
    const float* ln2s = (const float*)d_in[15];
    const float* ln2b = (const float*)d_in[16];

    char* ws = (char*)d_ws;
    const size_t MB = 1024 * 1024;
    ushort_t* wqkv = (ushort_t*)(ws + 0 * MB);   // wtq|wtk|wtv contiguous [3072][1024]
    ushort_t* wtq  = (ushort_t*)(ws + 0 * MB);
    ushort_t* wtk  = (ushort_t*)(ws + 2 * MB);
    ushort_t* wtv  = (ushort_t*)(ws + 4 * MB);
    ushort_t* wto  = (ushort_t*)(ws + 6 * MB);
    ushort_t* wt1  = (ushort_t*)(ws + 8 * MB);   // 8MB (4096x1024)
    ushort_t* wt2  = (ushort_t*)(ws + 16 * MB);  // 8MB (1024x4096)
    ushort_t* hbuf = (ushort_t*)(ws + 24 * MB);  // 8MB
    ushort_t* qb_  = (ushort_t*)(ws + 32 * MB);  // 8MB
    ushort_t* kb_  = (ushort_t*)(ws + 40 * MB);  // 8MB
    ushort_t* ctx  = (ushort_t*)(ws + 56 * MB);  // 8MB
    ushort_t* hid  = (ushort_t*)(ws + 32 * MB);  // 32MB, reuses q/k/ctx post-attn
    float*    x1   = (float*)(ws + 64 * MB);     // 16MB fp32 (written after attn)
    ushort_t* vtb  = (ushort_t*)(ws + 64 * MB);  // 8MB [1024][4096], dead after attn

    transpose_all_k<<<12288, dim3(32, 8), 0, stream>>>(Wq, Wk, Wv, Wo, W1, W2,
                                                       wtq, wtk, wtv, wto, wt1, wt2);

    ln_kernel<<<4096, 256, 0, stream>>>(x, ln1s, ln1b, hbuf);

    // fused QKV (dbuf m97 + swizzle + bounce epilogue); seg2 -> v^T in vtb
    gemm_bt<4, 3><<<dim3(24, 32), 256, 0, stream>>>(hbuf, wqkv, bq, bk, bv, nullptr,
                                                    qb_, kb_, vtb, 4096, 3072, 1024);

    attn_kernel<<<1024, 256, 0, stream>>>(qb_, kb_, vtb, ctx);

    // Wo projection: x1 = x + bo + ctx @ Wo^T
    gemm_bt<2, 1><<<dim3(8, 64), 256, 0, stream>>>(ctx, wto, bo, nullptr, nullptr, x,
                                                   x1, nullptr, nullptr, 4096, 1024, 1024);

    ln_kernel<<<4096, 256, 0, stream>>>(x1, ln2s, ln2b, hbuf);

    // FF1 (dbuf m97 + swizzle, gelu + bounce epilogue)
    gemm_bt<4, 2><<<dim3(32, 32), 256, 0, stream>>>(hbuf, wt1, b1, nullptr, nullptr, nullptr,
                                                    hid, nullptr, nullptr, 4096, 4096, 1024);

    // FF2: d_out = x1 + b2 + hid @ W2^T
    gemm_bt<2, 1><<<dim3(8, 64), 256, 0, stream>>>(hid, wt2, b2, nullptr, nullptr, x1,
                                                   (float*)d_out, nullptr, nullptr, 4096, 1024, 4096);
}

// Round 8
// 355.972 us; speedup vs baseline: 1.0573x; 1.0573x over previous
//
#include <hip/hip_runtime.h>
#include <hip/hip_bf16.h>
#include <stdint.h>

#define B_ 2
#define T_ 2048
#define C_ 1024
#define H_ 16
#define D_ 64
#define F_ 4096
#define M_ (B_*T_)

typedef unsigned short ushort_t;
typedef __attribute__((ext_vector_type(8))) short short8;
typedef __attribute__((ext_vector_type(4))) float f32x4;

__device__ __forceinline__ float bf2f(ushort_t u) {
    union { unsigned u; float f; } c; c.u = ((unsigned)u) << 16; return c.f;
}
__device__ __forceinline__ ushort_t f2bf(float f) {
    union { float f; unsigned u; } c; c.f = f;
    unsigned u = c.u;
    unsigned r = (u + 0x7FFFu + ((u >> 16) & 1u)) >> 16;
    return (ushort_t)r;
}

__device__ __forceinline__ float fexp2(float x) { return __builtin_amdgcn_exp2f(x); }

// async global->LDS, 16B per lane. LDS dest = wave-uniform base + lane*16.
__device__ __forceinline__ void async16(void* lds, const void* g) {
    __builtin_amdgcn_global_load_lds(
        (const __attribute__((address_space(1))) unsigned int*)(uintptr_t)g,
        (__attribute__((address_space(3))) unsigned int*)(uintptr_t)lds,
        16, 0, 0);
}

template <int N>
__device__ __forceinline__ void wait_vm() {
    if constexpr (N == 0) asm volatile("s_waitcnt vmcnt(0)" ::: "memory");
    else if constexpr (N == 3) asm volatile("s_waitcnt vmcnt(3)" ::: "memory");
    else if constexpr (N == 4) asm volatile("s_waitcnt vmcnt(4)" ::: "memory");
    else if constexpr (N == 6) asm volatile("s_waitcnt vmcnt(6)" ::: "memory");
}

// ---------------------------------------------------------------------------
// Batched transpose+cast of all 6 weights: out_bf16[c][r] = in_f32[r][c]
// ---------------------------------------------------------------------------
__global__ __launch_bounds__(256) void transpose_all_k(
    const float* __restrict__ Wq, const float* __restrict__ Wk,
    const float* __restrict__ Wv, const float* __restrict__ Wo,
    const float* __restrict__ W1, const float* __restrict__ W2,
    ushort_t* __restrict__ oq, ushort_t* __restrict__ ok,
    ushort_t* __restrict__ ov, ushort_t* __restrict__ oo,
    ushort_t* __restrict__ o1, ushort_t* __restrict__ o2) {
    __shared__ ushort_t tile[32][33];
    int id = blockIdx.x;
    const float* in; ushort_t* out; int R, Cc, bx, by;
    if (id < 4096) {
        int w = id >> 10, loc = id & 1023;
        in  = w == 0 ? Wq : w == 1 ? Wk : w == 2 ? Wv : Wo;
        out = w == 0 ? oq : w == 1 ? ok : w == 2 ? ov : oo;
        R = 1024; Cc = 1024; bx = loc & 31; by = loc >> 5;
    } else if (id < 8192) {
        int loc = id - 4096; in = W1; out = o1; R = 1024; Cc = 4096;
        bx = loc & 127; by = loc >> 7;
    } else {
        int loc = id - 8192; in = W2; out = o2; R = 4096; Cc = 1024;
        bx = loc & 31; by = loc >> 5;
    }
    int tx = threadIdx.x, ty = threadIdx.y;
    int x = bx * 32 + tx;
    int y0 = by * 32;
#pragma unroll
    for (int i = 0; i < 32; i += 8)
        tile[ty + i][tx] = f2bf(in[(size_t)(y0 + ty + i) * Cc + x]);
    __syncthreads();
    int x2 = y0 + tx;
    int y2 = bx * 32;
#pragma unroll
    for (int i = 0; i < 32; i += 8)
        out[(size_t)(y2 + ty + i) * R + x2] = tile[tx][ty + i];
}

// ---------------------------------------------------------------------------
// LayerNorm: fp32 input row of 1024, fp32 scale/shift, bf16 output.
// ---------------------------------------------------------------------------
__global__ __launch_bounds__(256) void ln_kernel(const float* __restrict__ xin,
                                                 const float* __restrict__ scale_p,
                                                 const float* __restrict__ shift_p,
                                                 ushort_t* __restrict__ out) {
    int row = blockIdx.x, t = threadIdx.x;
    int wv = t >> 6, lane = t & 63;
    const float* xr = xin + (size_t)row * 1024 + t * 4;
    float4 v = *(const float4*)xr;
    float f[4] = {v.x, v.y, v.z, v.w};
    float s = f[0] + f[1] + f[2] + f[3];
    float q = f[0]*f[0] + f[1]*f[1] + f[2]*f[2] + f[3]*f[3];
#pragma unroll
    for (int off = 1; off < 64; off <<= 1) {
        s += __shfl_xor(s, off, 64);
        q += __shfl_xor(q, off, 64);
    }
    __shared__ float sh_s[4], sh_q[4];
    if (lane == 0) { sh_s[wv] = s; sh_q[wv] = q; }
    __syncthreads();
    float S = sh_s[0] + sh_s[1] + sh_s[2] + sh_s[3];
    float Q = sh_q[0] + sh_q[1] + sh_q[2] + sh_q[3];
    float mean = S * (1.0f / 1024.0f);
    float var = Q * (1.0f / 1024.0f) - mean * mean;
    float rstd = rsqrtf(var + 1e-5f);
    float4 scv = *(const float4*)(scale_p + t * 4);
    float4 shv = *(const float4*)(shift_p + t * 4);
    ushort4 o;
    o.x = f2bf((f[0] - mean) * rstd * scv.x + shv.x);
    o.y = f2bf((f[1] - mean) * rstd * scv.y + shv.y);
    o.z = f2bf((f[2] - mean) * rstd * scv.z + shv.z);
    o.w = f2bf((f[3] - mean) * rstd * scv.w + shv.w);
    *(ushort4*)(out + (size_t)row * 1024 + t * 4) = o;
}

// ---------------------------------------------------------------------------
// GEMM, TRIPLE-buffered + counted-vmcnt pipeline (T3+T4 minimum recipe):
//   prologue: STAGE(b0,k0); STAGE(b1,k1); vmcnt(LPT); barrier;
//   iter k:   STAGE(b(k+2), k+2); reads+MFMA on b(k);
//             lgkmcnt(0); vmcnt(LPT) [counted, never 0 mid-loop];
//             sched_barrier; s_barrier.
// Loads get 2 full iterations to land (was 1-deep: __syncthreads drained
// vmcnt(0) right after issue -> full load latency exposed every iter, R7
// counters MfmaUtil 19.5%). LPT = MT/2+2 loads/tile/thread; FIFO audit:
// at each barrier exactly the next tile's loads retire, deeper stay live.
// Buffer hazard: iter k+1 stages into b((k+3)%3)=b(k%3), whose reads
// retired at iter k's lgkmcnt(0) before the barrier.
// Staging/read chunk swizzle (0 conflicts, R6) + LDS-bounce coalesced bf16
// epilogue (full-line writes, R7) + XCD-chunked block swizzle.
// C[M,N] = A[M,K](bf16) @ Bt[N,K](bf16)^T + bias; tile (32*MT) x 128, BK=32.
// EPI: 1 = +f32 residual, f32 out; 2 = gelu, bf16 out
//      3 = QKV split: seg0/1 -> q,k row-major bf16 [.][1024]; seg2 -> v^T
// ---------------------------------------------------------------------------
template <int MT, int EPI>
__global__ __launch_bounds__(256) void gemm_bt(const ushort_t* __restrict__ A,
                                               const ushort_t* __restrict__ Bt,
                                               const float* __restrict__ b0,
                                               const float* __restrict__ b1,
                                               const float* __restrict__ b2,
                                               const float* __restrict__ res,
                                               void* __restrict__ out0,
                                               void* __restrict__ out1,
                                               void* __restrict__ out2,
                                               int M, int N, int K) {
    // 3 staging buffers: As 3x(32*MT*32), Bs 3x(128*32); epilogue bounce reuses
    __shared__ ushort_t smem[3 * (1024 * MT + 4096)];
    ushort_t* As = smem;
    ushort_t* Bs = smem + 3 * 1024 * MT;
    constexpr int LPT = MT / 2 + 2;   // loads per tile per thread
    const int t = threadIdx.x;
    const int wv = t >> 6, lane = t & 63, lo = lane & 15, hi = lane >> 4;
    const int wr = wv >> 1, wc = wv & 1;
    const int swz8 = (hi ^ ((lo >> 1) & 3)) * 8;   // read-side chunk swizzle

    // XCD-chunked swizzle (dispatch id d -> XCD d%8; give each XCD a
    // contiguous chunk of the x-major tile order = complete row-panels)
    const int nwg = gridDim.x * gridDim.y;
    const int id = blockIdx.y * gridDim.x + blockIdx.x;
    const int swz = (id & 7) * (nwg >> 3) + (id >> 3);
    const int nb = swz % gridDim.x, mb = swz / gridDim.x;

    f32x4 acc[MT][4];
#pragma unroll
    for (int i = 0; i < MT; ++i)
#pragma unroll
        for (int j = 0; j < 4; ++j) acc[i][j] = (f32x4){0.f, 0.f, 0.f, 0.f};

    auto STAGE = [&](int bf, int k0) {
#pragma unroll
        for (int i = 0; i < MT / 2; ++i) {
            int c = i * 256 + t;
            int row = c >> 2, kc = c & 3;
            int kof = (kc ^ ((row >> 1) & 3)) * 8;   // pre-swizzled source chunk
            async16((char*)(As + bf * 1024 * MT) + (size_t)(i * 256 + wv * 64) * 16,
                    A + (size_t)(mb * 32 * MT + row) * K + k0 + kof);
        }
#pragma unroll
        for (int i = 0; i < 2; ++i) {
            int c = i * 256 + t;
            int row = c >> 2, kc = c & 3;
            int kof = (kc ^ ((row >> 1) & 3)) * 8;
            async16((char*)(Bs + bf * 4096) + (size_t)(i * 256 + wv * 64) * 16,
                    Bt + (size_t)(nb * 128 + row) * K + k0 + kof);
        }
    };

    const int NI = K >> 5;   // always >= 32 here
    STAGE(0, 0);
    STAGE(1, 32);
    wait_vm<LPT>();          // tile0 landed; tile1's LPT loads stay in flight
    __builtin_amdgcn_sched_barrier(0);
    __builtin_amdgcn_s_barrier();

    int bf = 0, bs = 2;
    for (int ki = 0; ki < NI; ++ki) {
        if (ki + 2 < NI) STAGE(bs, (ki + 2) << 5);

        short8 af[MT], bfr[4];
#pragma unroll
        for (int mi = 0; mi < MT; ++mi)
            af[mi] = *(const short8*)(As + bf * 1024 * MT + (wr * 16 * MT + mi * 16 + lo) * 32 + swz8);
#pragma unroll
        for (int ni = 0; ni < 4; ++ni)
            bfr[ni] = *(const short8*)(Bs + bf * 4096 + (wc * 64 + ni * 16 + lo) * 32 + swz8);
#pragma unroll
        for (int mi = 0; mi < MT; ++mi)
#pragma unroll
            for (int ni = 0; ni < 4; ++ni)
                acc[mi][ni] = __builtin_amdgcn_mfma_f32_16x16x32_bf16(
                    af[mi], bfr[ni], acc[mi][ni], 0, 0, 0);

        asm volatile("s_waitcnt lgkmcnt(0)" ::: "memory");  // own reads retired
        if (ki + 2 < NI) wait_vm<LPT>();                    // counted: next tile ready
        else             wait_vm<0>();                      // tail drain
        __builtin_amdgcn_sched_barrier(0);
        __builtin_amdgcn_s_barrier();
        bf = (bf == 2) ? 0 : bf + 1;
        bs = (bs == 2) ? 0 : bs + 1;
    }

    // ------------------------- epilogue -------------------------
    if (EPI == 1) {
        // f32 + residual: quarter-wave = 64B full lines, already coalesced
#pragma unroll
        for (int ni = 0; ni < 4; ++ni) {
            int n = nb * 128 + wc * 64 + ni * 16 + lo;
            float bn = b0[n];
#pragma unroll
            for (int mi = 0; mi < MT; ++mi)
#pragma unroll
                for (int r = 0; r < 4; ++r) {
                    int m = mb * 32 * MT + wr * 16 * MT + mi * 16 + 4 * hi + r;
                    size_t idx = (size_t)m * N + n;
                    ((float*)out0)[idx] = acc[mi][ni][r] + bn + res[idx];
                }
        }
        return;
    }

    if (EPI == 3 && nb >= 16) {
        // seg 2: v^T transposed ushort4 store
#pragma unroll
        for (int ni = 0; ni < 4; ++ni) {
            int n = nb * 128 + wc * 64 + ni * 16 + lo;
            int coln = n & 1023;
            float bn = b2[coln];
#pragma unroll
            for (int mi = 0; mi < MT; ++mi) {
                int m0 = mb * 32 * MT + wr * 16 * MT + mi * 16 + 4 * hi;
                ushort4 pk;
                pk.x = f2bf(acc[mi][ni][0] + bn);
                pk.y = f2bf(acc[mi][ni][1] + bn);
                pk.z = f2bf(acc[mi][ni][2] + bn);
                pk.w = f2bf(acc[mi][ni][3] + bn);
                *(ushort4*)((ushort_t*)out2 + (size_t)coln * M + m0) = pk;
            }
        }
        return;
    }

    // bf16 row-major (EPI==2, or EPI==3 seg 0/1): LDS-bounce coalesced store
    {
        ushort_t* obf;
        const float* bias;
        int rowlen;
        if (EPI == 3) {
            int seg = nb >> 3;
            obf = (ushort_t*)(seg ? out1 : out0);
            bias = seg ? b1 : b0;
            rowlen = 1024;
        } else {
            obf = (ushort_t*)out0;
            bias = b0;
            rowlen = N;
        }
        // write acc -> LDS tile [32*MT][128], chunk-swizzled (conflict-free)
#pragma unroll
        for (int ni = 0; ni < 4; ++ni) {
            int n = nb * 128 + wc * 64 + ni * 16 + lo;
            float bn = bias[EPI == 3 ? (n & 1023) : n];
#pragma unroll
            for (int mi = 0; mi < MT; ++mi)
#pragma unroll
                for (int r = 0; r < 4; ++r) {
                    float v = acc[mi][ni][r] + bn;
                    if (EPI == 2)
                        v = 0.5f * v * (1.0f + erff(v * 0.70710678118654752f));
                    int row = wr * 16 * MT + mi * 16 + 4 * hi + r;
                    int c8 = (wc * 8 + ni * 2 + (lo >> 3)) ^ (hi << 1);
                    smem[row * 128 + c8 * 8 + (lo & 7)] = f2bf(v);
                }
        }
        __syncthreads();
        // read short8 + store 256B-contiguous rows (full lines)
        const int TR = 2 * MT;   // (32*MT*16)/256
#pragma unroll
        for (int j = 0; j < TR; ++j) {
            int idx = j * 256 + t;
            int row = idx >> 4, c = idx & 15;
            int c_src = c ^ (((row >> 2) & 3) << 1);
            short8 val = *(const short8*)(smem + row * 128 + c_src * 8);
            int m = mb * 32 * MT + row;
            int ncol = nb * 128 + c * 8;
            if (EPI == 3) ncol &= 1023;
            *(short8*)(obf + (size_t)m * rowlen + ncol) = val;
        }
    }
}

// ---------------------------------------------------------------------------
// Causal flash attention: 64-row q-tiles, grid 1024 (32 qt x 32 bh),
// longest strips dispatched first; 4 blocks/CU (LDS = 40960).
// ---------------------------------------------------------------------------
__global__ __launch_bounds__(256) void attn_kernel(const ushort_t* __restrict__ q,
                                                   const ushort_t* __restrict__ k,
                                                   const ushort_t* __restrict__ vt,
                                                   ushort_t* __restrict__ ctx) {
    __shared__ ushort_t Ks[2][64 * 64];   // [buf][key][d], col-chunk swizzled
    __shared__ ushort_t VTs[2][64 * 64];  // [buf][d][key], col-chunk swizzled
    __shared__ ushort_t Ps[4][16 * 64];   // [wave][qrow][key], XOR-swizzled chunks

    const int t = threadIdx.x;
    const int wv = t >> 6, lane = t & 63, lo = lane & 15, hi = lane >> 4;
    const int id = blockIdx.x;             // 1024
    const int qt = 31 - (id >> 5);         // longest-first
    const int bh = id & 31, b = bh >> 4, h = bh & 15;
    const int q0 = qt * 64;
    const size_t headoff = (size_t)h * 64;
    const size_t rowbase = (size_t)b * T_ * 1024;
    const ushort_t* vbase = vt + headoff * (size_t)M_ + (size_t)b * T_;

    short8 qf[2];
    {
        const ushort_t* qp = q + rowbase + (size_t)(q0 + wv * 16 + lo) * 1024 + headoff;
        qf[0] = *(const short8*)(qp + hi * 8);
        qf[1] = *(const short8*)(qp + 32 + hi * 8);
    }

    float m_r = -1e30f, l_r = 0.f;
    f32x4 o_acc[4];
#pragma unroll
    for (int dt = 0; dt < 4; ++dt) o_acc[dt] = (f32x4){0.f, 0.f, 0.f, 0.f};

    const float SC = 0.18033688011112042f;  // 0.125 * log2(e)
    const f32x4 NEG4 = (f32x4){-1e30f, -1e30f, -1e30f, -1e30f};

    auto stage = [&](int bb, int kt) {
        const int k0s = kt * 64;
#pragma unroll
        for (int i = 0; i < 2; ++i) {
            int c = i * 256 + t;
            int row = c >> 3, c8 = c & 7;
            int gsw = c8 ^ (row & 7);
            async16((char*)&Ks[bb][0] + (size_t)(i * 256 + wv * 64) * 16,
                    k + rowbase + (size_t)(k0s + row) * 1024 + headoff + gsw * 8);
            async16((char*)&VTs[bb][0] + (size_t)(i * 256 + wv * 64) * 16,
                    vbase + (size_t)row * M_ + k0s + gsw * 8);
        }
    };

    ushort_t* Pw = Ps[wv];
    const int psw = lo & 7;

    stage(0, 0);
    for (int kt = 0; kt <= qt; ++kt) {
        const int bb = kt & 1;
        const int k0 = kt * 64;
        __syncthreads();
        if (kt < qt) stage(bb ^ 1, kt + 1);

        const int diff = q0 + wv * 16 - k0;   // >= 0 always (kt <= qt)
        const int cmax = diff >= 48 ? 3 : (diff >> 4);

        f32x4 sacc[4];
#pragma unroll
        for (int kt16 = 0; kt16 < 4; ++kt16) {
            if (kt16 <= cmax) {
                int row = kt16 * 16 + lo, sw = row & 7;
                short8 kf0 = *(const short8*)(&Ks[bb][0] + row * 64 + (hi ^ sw) * 8);
                short8 kf1 = *(const short8*)(&Ks[bb][0] + row * 64 + ((4 + hi) ^ sw) * 8);
                f32x4 z = (f32x4){0.f, 0.f, 0.f, 0.f};
                z = __builtin_amdgcn_mfma_f32_16x16x32_bf16(kf0, qf[0], z, 0, 0, 0);
                z = __builtin_amdgcn_mfma_f32_16x16x32_bf16(kf1, qf[1], z, 0, 0, 0);
#pragma unroll
                for (int r = 0; r < 4; ++r) sacc[kt16][r] = z[r] * SC;
            } else {
                sacc[kt16] = NEG4;
            }
        }
        if (diff < 64) {  // diagonal subtile: element mask key > qrow
            const int qrow = diff + lo;
#pragma unroll
            for (int r = 0; r < 4; ++r) {
                int key = cmax * 16 + 4 * hi + r;
                if (key > qrow) sacc[cmax][r] = -1e30f;
            }
        }

        // ---- online softmax (rows = lo), packed P spill ----
        float mx = -1e30f;
#pragma unroll
        for (int kt16 = 0; kt16 < 4; ++kt16)
#pragma unroll
            for (int r = 0; r < 4; ++r) mx = fmaxf(mx, sacc[kt16][r]);
        mx = fmaxf(mx, __shfl_xor(mx, 16, 64));
        mx = fmaxf(mx, __shfl_xor(mx, 32, 64));
        float mnew = fmaxf(m_r, mx);
        float alpha = fexp2(m_r - mnew);
        m_r = mnew;
        float rs = 0.f;
#pragma unroll
        for (int kt16 = 0; kt16 < 4; ++kt16) {
            float p0 = fexp2(sacc[kt16][0] - mnew);
            float p1 = fexp2(sacc[kt16][1] - mnew);
            float p2 = fexp2(sacc[kt16][2] - mnew);
            float p3 = fexp2(sacc[kt16][3] - mnew);
            rs += p0 + p1 + p2 + p3;
            ushort4 pk;
            pk.x = f2bf(p0); pk.y = f2bf(p1); pk.z = f2bf(p2); pk.w = f2bf(p3);
            // key s = kt16*16 + 4*hi + r -> chunk 2*kt16 + (hi>>1), offset 4*(hi&1)
            *(ushort4*)(Pw + lo * 64 + (((2 * kt16 + (hi >> 1)) ^ psw) << 3) + 4 * (hi & 1)) = pk;
        }
        rs += __shfl_xor(rs, 16, 64);
        rs += __shfl_xor(rs, 32, 64);
        l_r = l_r * alpha + rs;
#pragma unroll
        for (int r = 0; r < 4; ++r) {
            float ab = __shfl(alpha, 4 * hi + r, 64);
#pragma unroll
            for (int dt = 0; dt < 4; ++dt) o_acc[dt][r] *= ab;
        }

        // ---- read P fragments back (same-wave LDS, in-order) ----
        short8 pf0 = *(const short8*)(Pw + lo * 64 + ((hi ^ psw) << 3));
        short8 pf1 = *(const short8*)(Pw + lo * 64 + (((4 + hi) ^ psw) << 3));

        // ---- PV ----
#pragma unroll
        for (int dt = 0; dt < 4; ++dt) {
            int row = dt * 16 + lo, sw = row & 7;
            short8 vf0 = *(const short8*)(&VTs[bb][0] + row * 64 + (hi ^ sw) * 8);
            short8 vf1 = *(const short8*)(&VTs[bb][0] + row * 64 + ((4 + hi) ^ sw) * 8);
            o_acc[dt] = __builtin_amdgcn_mfma_f32_16x16x32_bf16(pf0, vf0, o_acc[dt], 0, 0, 0);
            o_acc[dt] = __builtin_amdgcn_mfma_f32_16x16x32_bf16(pf1, vf1, o_acc[dt], 0, 0, 0);
        }
    }

#pragma unroll
    for (int r = 0; r < 4; ++r) {
        float lb = __shfl(l_r, 4 * hi + r, 64);
        float inv = 1.0f / lb;
        size_t row = rowbase + (size_t)(q0 + wv * 16 + 4 * hi + r) * 1024 + headoff;
#pragma unroll
        for (int dt = 0; dt < 4; ++dt)
            ctx[row + dt * 16 + lo] = f2bf(o_acc[dt][r] * inv);
    }
}

// ---------------------------------------------------------------------------
extern "C" void kernel_launch(void* const* d_in, const int* in_sizes, int n_in,
                              void* d_out, int out_size, void* d_ws, size_t ws_size,
                              hipStream_t stream) {
    (void)in_sizes; (void)n_in; (void)out_size; (void)ws_size;
    const float* x    = (const float*)d_in[0];
    const float* Wq   = (const float*)d_in[1];
    const float* bq   = (const float*)d_in[2];
    const float* Wk   = (const float*)d_in[3];
    const float* bk   = (const float*)d_in[4];
    const float* Wv   = (const float*)d_in[5];
    const float* bv   = (const float*)d_in[6];
    const float* Wo   = (const float*)d_in[7];
    const float* bo   = (const float*)d_in[8];
    const float* W1   = (const float*)d_in[9];
    const float* b1   = (const float*)d_in[10];
    const float* W2   = (const float*)d_in[11];
    const float* b2   = (const float*)d_in[12];
    const float* ln1s = (const float*)d_in[13];
    const float* ln1b = (const float*)d_in[14];
    const float* ln2s = (const float*)d_in[15];
    const float* ln2b = (const float*)d_in[16];

    char* ws = (char*)d_ws;
    const size_t MB = 1024 * 1024;
    ushort_t* wqkv = (ushort_t*)(ws + 0 * MB);   // wtq|wtk|wtv contiguous [3072][1024]
    ushort_t* wtq  = (ushort_t*)(ws + 0 * MB);
    ushort_t* wtk  = (ushort_t*)(ws + 2 * MB);
    ushort_t* wtv  = (ushort_t*)(ws + 4 * MB);
    ushort_t* wto  = (ushort_t*)(ws + 6 * MB);
    ushort_t* wt1  = (ushort_t*)(ws + 8 * MB);   // 8MB (4096x1024)
    ushort_t* wt2  = (ushort_t*)(ws + 16 * MB);  // 8MB (1024x4096)
    ushort_t* hbuf = (ushort_t*)(ws + 24 * MB);  // 8MB
    ushort_t* qb_  = (ushort_t*)(ws + 32 * MB);  // 8MB
    ushort_t* kb_  = (ushort_t*)(ws + 40 * MB);  // 8MB
    ushort_t* ctx  = (ushort_t*)(ws + 56 * MB);  // 8MB
    ushort_t* hid  = (ushort_t*)(ws + 32 * MB);  // 32MB, reuses q/k/ctx post-attn
    float*    x1   = (float*)(ws + 64 * MB);     // 16MB fp32 (written after attn)
    ushort_t* vtb  = (ushort_t*)(ws + 64 * MB);  // 8MB [1024][4096], dead after attn

    transpose_all_k<<<12288, dim3(32, 8), 0, stream>>>(Wq, Wk, Wv, Wo, W1, W2,
                                                       wtq, wtk, wtv, wto, wt1, wt2);

    ln_kernel<<<4096, 256, 0, stream>>>(x, ln1s, ln1b, hbuf);

    // fused QKV (triple-buf counted-vmcnt); seg2 -> v^T in vtb
    gemm_bt<4, 3><<<dim3(24, 32), 256, 0, stream>>>(hbuf, wqkv, bq, bk, bv, nullptr,
                                                    qb_, kb_, vtb, 4096, 3072, 1024);

    attn_kernel<<<1024, 256, 0, stream>>>(qb_, kb_, vtb, ctx);

    // Wo projection: x1 = x + bo + ctx @ Wo^T
    gemm_bt<2, 1><<<dim3(8, 64), 256, 0, stream>>>(ctx, wto, bo, nullptr, nullptr, x,
                                                   x1, nullptr, nullptr, 4096, 1024, 1024);

    ln_kernel<<<4096, 256, 0, stream>>>(x1, ln2s, ln2b, hbuf);

    // FF1 (triple-buf counted-vmcnt, gelu + bounce epilogue)
    gemm_bt<4, 2><<<dim3(32, 32), 256, 0, stream>>>(hbuf, wt1, b1, nullptr, nullptr, nullptr,
                                                    hid, nullptr, nullptr, 4096, 4096, 1024);

    // FF2: d_out = x1 + b2 + hid @ W2^T
    gemm_bt<2, 1><<<dim3(8, 64), 256, 0, stream>>>(hid, wt2, b2, nullptr, nullptr, x1,
                                                   (float*)d_out, nullptr, nullptr, 4096, 1024, 4096);
}